// Round 12
// baseline (608.399 us; speedup 1.0000x reference)
//
#include <hip/hip_runtime.h>
#include <cstddef>

// Shapes (hard-coded): B=2, L=4096 (64x64), C=256, H=8, D=32, K=9, scale=8,
// layers: self,cross,self,cross. X rows: 0..8191 feat0 (b0,b1), 8192..16383 feat1.

#define NROWS 16384

typedef unsigned short ushort_t;
typedef __attribute__((ext_vector_type(8))) short short8;
typedef __attribute__((ext_vector_type(4))) float f32x4;
typedef __attribute__((ext_vector_type(4))) unsigned short ushort4_t;
typedef __attribute__((ext_vector_type(8))) unsigned short ushort8_t;
typedef _Float16 half_t;
typedef __attribute__((ext_vector_type(4))) _Float16 half4;
typedef __attribute__((ext_vector_type(8))) _Float16 half8;

__device__ __forceinline__ float b2f(unsigned short u) {
    union { unsigned int i; float f; } v; v.i = (unsigned int)u << 16; return v.f;
}
__device__ __forceinline__ unsigned short f2b(float x) {
    union { float f; unsigned int i; } v; v.f = x;
    unsigned int r = v.i + 0x7fffu + ((v.i >> 16) & 1u);   // RNE
    return (unsigned short)(r >> 16);
}
__device__ __forceinline__ ushort_t f2h(float x) {
    union { half_t h; ushort_t u; } v; v.h = (half_t)x; return v.u;   // v_cvt_f16_f32 RNE
}
// elu(x)+1: for x<=0, elu = exp(x)-1, so elu+1 = exp(x) exactly.
__device__ __forceinline__ float elu1(float x) {
    return x > 0.f ? x + 1.f : __expf(x);
}

#define ASYNC_COPY16(gptr, lptr) \
    __builtin_amdgcn_global_load_lds((const __attribute__((address_space(1))) void*)(gptr), \
                                     (__attribute__((address_space(3))) void*)(lptr), 16, 0, 0)

// ---------------------------------------------------------------------------
// Weights stored FRAGMENT-MAJOR ("TF"): for Wt[N][K] (bf16), granule order =
// [k-panel of 32][n-group of 16][quad = k-granule 0..3][l16 = n&15]:
// offset(n,k) = ((k>>5)*(N>>4) + (n>>4))*512 + ((k>>3)&3)*128 + (n&15)*8 + (k&7).
// Staging is a LINEAR global_load_lds copy; MFMA B-read touches 64 distinct
// consecutive granules.
// ---------------------------------------------------------------------------

// bf16 MFMA GEMM: C[M,N] = A[M,K] @ Wt(TF). 128x128 tile, BK=64. Used ONLY
// for layer 0's QKV projection now (layers 1-3 QKV fused into mlp).
// Side duty: blocks with blockIdx.y==0 zero the KVb/KSb accumulators.
__global__ __launch_bounds__(256) void gemm_bf16_kernel(
    const ushort_t* __restrict__ A0, int lda0,
    const ushort_t* __restrict__ Wt, int ldw,
    ushort_t* __restrict__ C, int ldc, int Kd,
    float* __restrict__ zbuf, int znf4)   // zero zbuf[0..znf4*4) floats
{
    __shared__ ushort_t As[128 * 64];   // 16 KB
    __shared__ ushort_t Bs[128 * 64];   // 16 KB

    int tid = threadIdx.x;
    int m0 = blockIdx.y * 128;
    int n0 = blockIdx.x * 128;
    int lane = tid & 63, w = tid >> 6;
    int wrow = w >> 1, wcol = w & 1;
    int quad = lane >> 4, l16 = lane & 15;

    if (zbuf && blockIdx.y == 0) {
        int nblk = gridDim.x;
        for (int i = blockIdx.x * 256 + tid; i < znf4; i += nblk * 256)
            *(float4*)&zbuf[(size_t)i * 4] = (float4){0.f, 0.f, 0.f, 0.f};
    }

    f32x4 acc[4][4];
    #pragma unroll
    for (int i = 0; i < 4; i++)
        #pragma unroll
        for (int j = 0; j < 4; j++) acc[i][j] = (f32x4){0.f, 0.f, 0.f, 0.f};

    for (int kb = 0; kb < Kd; kb += 64) {
        #pragma unroll
        for (int q = 0; q < 4; q++) {
            int s = q * 256 + tid;
            int kk = s >> 9, p = s & 511;
            int row = p >> 2, c4 = p & 3;
            ASYNC_COPY16(A0 + (size_t)(m0 + row) * lda0 + kb + kk * 32 + c4 * 8,
                         (char*)As + s * 16);
        }
        // B: TF layout, N=768 (48 n-groups). Linear copy of sub-panels.
        #pragma unroll
        for (int q = 0; q < 4; q++) {
            int s = q * 256 + tid;
            int kk = s >> 9, p = s & 511;
            int rg = p >> 6, gi = p & 63;
            ASYNC_COPY16(Wt + (((size_t)((kb >> 5) + kk) * 48 + (n0 >> 4) + rg) * 512 + gi * 8),
                         (char*)Bs + s * 16);
        }
        __syncthreads();

        #pragma unroll
        for (int kk = 0; kk < 2; kk++) {
            short8 af[4], bf[4];
            #pragma unroll
            for (int mt = 0; mt < 4; mt++)
                af[mt] = *(const short8*)&As[kk * 4096 + (wrow * 64 + mt * 16 + l16) * 32 + quad * 8];
            #pragma unroll
            for (int nt = 0; nt < 4; nt++)
                bf[nt] = *(const short8*)&Bs[kk * 4096 + (wcol * 4 + nt) * 512 + (quad * 16 + l16) * 8];
            #pragma unroll
            for (int mt = 0; mt < 4; mt++)
                #pragma unroll
                for (int nt = 0; nt < 4; nt++)
                    acc[mt][nt] = __builtin_amdgcn_mfma_f32_16x16x32_bf16(
                        af[mt], bf[nt], acc[mt][nt], 0, 0, 0);
        }
        __syncthreads();
    }

    #pragma unroll
    for (int mt = 0; mt < 4; mt++) {
        int row = m0 + wrow * 64 + mt * 16 + quad * 4;
        #pragma unroll
        for (int nt = 0; nt < 4; nt++) {
            int col = n0 + wcol * 64 + nt * 16 + l16;
            #pragma unroll
            for (int r = 0; r < 4; r++)
                C[(size_t)(row + r) * ldc + col] = f2h(acc[mt][nt][r]);
        }
    }
}

// ---------------------------------------------------------------------------
// FULLY FUSED ln1 + MLP + ln2 + residual + NEXT-LAYER QKV PROJECTION.
// (see R11 notes) LDS 77K -> 2 blocks/CU.
// ---------------------------------------------------------------------------
__global__ __launch_bounds__(256) void mlp_ln_fused_kernel(
    const ushort_t* __restrict__ MSG, const ushort_t* __restrict__ Wmt,
    const float* __restrict__ g1, const float* __restrict__ b1,
    const ushort_t* __restrict__ Xb,
    const ushort_t* __restrict__ W1t, const ushort_t* __restrict__ W2t,
    const float* __restrict__ g2, const float* __restrict__ bp,
    ushort_t* __restrict__ XbfOut, const float* __restrict__ Xin,
    float* __restrict__ Xout,
    const ushort_t* __restrict__ Wqkv, ushort_t* __restrict__ QKVout,
    float* __restrict__ zbuf, int znf4)
{
    __shared__ ushort_t XB[32 * 256];    // 16K  Xb rows (bf16), swizzled
    __shared__ ushort_t L1s[32 * 256];   // 16K  L1 rows (bf16), swizzled
    __shared__ ushort_t Tnp[32 * 128];   // 8K   current T chunk, swizzled
    __shared__ ushort_t Bs[256 * 64];    // 32K  staging: Wmt / W1t / W2t / Wqkv (TF)
    __shared__ ushort_t As[32 * 64];     // 4K   staging: MSG (phase A)
    __shared__ float stats[256];         // rsum[0:128] rsq[128:256]

    int tid = threadIdx.x;
    int m0 = blockIdx.x * 32;
    int lane = tid & 63, w = tid >> 6;
    int quad = lane >> 4, l16 = lane & 15;

    if (zbuf) {
        for (int ii = blockIdx.x * 256 + tid; ii < znf4; ii += gridDim.x * 256)
            *(float4*)&zbuf[(size_t)ii * 4] = (float4){0.f, 0.f, 0.f, 0.f};
    }

    // ---- XB staging: linear dest, pre-swizzled global source ----
    #pragma unroll
    for (int i = 0; i < 4; i++) {
        int s = i * 256 + tid;
        int row = s >> 5, gp = s & 31;          // dest granule within row
        int gsrc = gp ^ (row & 7);              // source granule
        ASYNC_COPY16(Xb + (size_t)(m0 + row) * 256 + gsrc * 8,
                     (char*)XB + s * 16);
    }

    // ---------- phase A: L1 = LN1(MSG @ Wmt) ----------
    f32x4 accA[2][4];
    #pragma unroll
    for (int i = 0; i < 2; i++)
        #pragma unroll
        for (int j = 0; j < 4; j++) accA[i][j] = (f32x4){0.f, 0.f, 0.f, 0.f};

    for (int kb = 0; kb < 256; kb += 64) {
        {
            int s = tid;
            int kk = s >> 7, p = s & 127;
            ASYNC_COPY16(MSG + (size_t)(m0 + (p >> 2)) * 256 + kb + kk * 32 + (p & 3) * 8,
                         (char*)As + s * 16);
        }
        // Wmt TF: N=256 (16 n-groups)
        #pragma unroll
        for (int q = 0; q < 8; q++) {
            int s = q * 256 + tid;
            int kk = s >> 10, p = s & 1023;
            int rg = p >> 6, gi = p & 63;
            ASYNC_COPY16(Wmt + (((size_t)((kb >> 5) + kk) * 16 + rg) * 512 + gi * 8),
                         (char*)Bs + s * 16);
        }
        __syncthreads();

        #pragma unroll
        for (int kk = 0; kk < 2; kk++) {
            short8 af[2], bf[4];
            #pragma unroll
            for (int mt = 0; mt < 2; mt++)
                af[mt] = *(const short8*)&As[kk * 1024 + (mt * 16 + l16) * 32 + quad * 8];
            #pragma unroll
            for (int nt = 0; nt < 4; nt++)
                bf[nt] = *(const short8*)&Bs[kk * 8192 + (w * 4 + nt) * 512 + (quad * 16 + l16) * 8];
            #pragma unroll
            for (int mt = 0; mt < 2; mt++)
                #pragma unroll
                for (int nt = 0; nt < 4; nt++)
                    accA[mt][nt] = __builtin_amdgcn_mfma_f32_16x16x32_bf16(
                        af[mt], bf[nt], accA[mt][nt], 0, 0, 0);
        }
        __syncthreads();
    }

    // LN1 stats + write L1s (swizzled)
    #pragma unroll
    for (int mt = 0; mt < 2; mt++)
        #pragma unroll
        for (int r = 0; r < 4; r++) {
            float s = 0.f, q = 0.f;
            #pragma unroll
            for (int nt = 0; nt < 4; nt++) {
                float v = accA[mt][nt][r];
                s += v; q += v * v;
            }
            #pragma unroll
            for (int off = 1; off < 16; off <<= 1) {
                s += __shfl_xor(s, off, 64);
                q += __shfl_xor(q, off, 64);
            }
            if (l16 == 0) {
                stats[w * 32 + mt * 16 + quad * 4 + r] = s;
                stats[128 + w * 32 + mt * 16 + quad * 4 + r] = q;
            }
        }
    __syncthreads();

    #pragma unroll
    for (int mt = 0; mt < 2; mt++) {
        #pragma unroll
        for (int r = 0; r < 4; r++) {
            int rl = mt * 16 + quad * 4 + r;
            float s = stats[rl] + stats[32 + rl] + stats[64 + rl] + stats[96 + rl];
            float q = stats[128 + rl] + stats[160 + rl] + stats[192 + rl] + stats[224 + rl];
            float m = s * (1.f / 256.f);
            float var = q * (1.f / 256.f) - m * m;
            float rs = rsqrtf(var + 1e-5f);
            #pragma unroll
            for (int nt = 0; nt < 4; nt++) {
                int col = w * 64 + nt * 16 + l16;
                float y = (accA[mt][nt][r] - m) * rs * g1[col] + b1[col];
                L1s[rl * 256 + (((col >> 3) ^ (rl & 7)) << 3) + (col & 7)] = f2b(y);
            }
        }
    }
    __syncthreads();

    // ---------- np loop: stage1 (Tnp) then stage2 partial-accumulate ----------
    f32x4 acc2[2][2][2];
    #pragma unroll
    for (int a = 0; a < 2; a++)
        #pragma unroll
        for (int i = 0; i < 2; i++)
            #pragma unroll
            for (int j = 0; j < 2; j++) acc2[a][i][j] = (f32x4){0.f, 0.f, 0.f, 0.f};

    #pragma unroll
    for (int np = 0; np < 4; np++) {
        // ----- stage1: Tnp = tanh([XB|L1s] @ W1t[np*128 .. +128]) -----
        f32x4 acc1[2][2];
        #pragma unroll
        for (int i = 0; i < 2; i++)
            #pragma unroll
            for (int j = 0; j < 2; j++) acc1[i][j] = (f32x4){0.f, 0.f, 0.f, 0.f};

        #pragma unroll
        for (int kb = 0; kb < 512; kb += 128) {
            // W1t TF: N=512 (32 n-groups); rows np*8..np*8+7
            #pragma unroll
            for (int q = 0; q < 8; q++) {
                int s = q * 256 + tid;
                int kk = s >> 9, p = s & 511;
                int rg = p >> 6, gi = p & 63;
                ASYNC_COPY16(W1t + (((size_t)((kb >> 5) + kk) * 32 + np * 8 + rg) * 512 + gi * 8),
                             (char*)Bs + s * 16);
            }
            __syncthreads();

            #pragma unroll
            for (int kk = 0; kk < 4; kk++) {
                short8 af[2], bfr[2];
                #pragma unroll
                for (int mt = 0; mt < 2; mt++) {
                    int row = mt * 16 + l16;
                    int k = kb + kk * 32 + quad * 8;
                    if (k < 256)
                        af[mt] = *(const short8*)&XB[row * 256 + (((k >> 3) ^ (row & 7)) << 3)];
                    else
                        af[mt] = *(const short8*)&L1s[row * 256 + ((((k - 256) >> 3) ^ (row & 7)) << 3)];
                }
                #pragma unroll
                for (int nt = 0; nt < 2; nt++)
                    bfr[nt] = *(const short8*)&Bs[kk * 4096 + (w * 2 + nt) * 512 + (quad * 16 + l16) * 8];
                #pragma unroll
                for (int mt = 0; mt < 2; mt++)
                    #pragma unroll
                    for (int nt = 0; nt < 2; nt++)
                        acc1[mt][nt] = __builtin_amdgcn_mfma_f32_16x16x32_bf16(
                            af[mt], bfr[nt], acc1[mt][nt], 0, 0, 0);
            }
            __syncthreads();
        }

        // tanh -> Tnp (swizzled)
        #pragma unroll
        for (int mt = 0; mt < 2; mt++)
            #pragma unroll
            for (int nt = 0; nt < 2; nt++)
                #pragma unroll
                for (int r = 0; r < 4; r++) {
                    int trow = mt * 16 + quad * 4 + r;
                    int c = w * 32 + nt * 16 + l16;     // local col 0..127
                    Tnp[trow * 128 + (((c >> 3) ^ (trow & 7)) << 3) + (c & 7)] =
                        f2b(tanhf(acc1[mt][nt][r]));
                }
        __syncthreads();

        // ----- stage2 partial: acc2 += Tnp @ W2t[k = np*128 .. +128] -----
        #pragma unroll
        for (int kb2 = 0; kb2 < 128; kb2 += 64) {
            // W2t TF: N=256 (16 n-groups); k-panels np*4 + kb2/32 + kk
            #pragma unroll
            for (int q = 0; q < 8; q++) {
                int s = q * 256 + tid;
                int kk = s >> 10, p = s & 1023;
                int rg = p >> 6, gi = p & 63;
                ASYNC_COPY16(W2t + (((size_t)(np * 4 + (kb2 >> 5) + kk) * 16 + rg) * 512 + gi * 8),
                             (char*)Bs + s * 16);
            }
            __syncthreads();

            #pragma unroll
            for (int kk = 0; kk < 2; kk++) {
                short8 af[2];
                #pragma unroll
                for (int mt = 0; mt < 2; mt++) {
                    int row = mt * 16 + l16;
                    int klocal = kb2 + kk * 32 + quad * 8;
                    af[mt] = *(const short8*)&Tnp[row * 128 + (((klocal >> 3) ^ (row & 7)) << 3)];
                }
                #pragma unroll
                for (int pass = 0; pass < 2; pass++)
                    #pragma unroll
                    for (int nt = 0; nt < 2; nt++) {
                        short8 bfr = *(const short8*)&Bs[kk * 8192 +
                            (pass * 8 + w * 2 + nt) * 512 + (quad * 16 + l16) * 8];
                        #pragma unroll
                        for (int mt = 0; mt < 2; mt++)
                            acc2[pass][mt][nt] = __builtin_amdgcn_mfma_f32_16x16x32_bf16(
                                af[mt], bfr, acc2[pass][mt][nt], 0, 0, 0);
                    }
            }
            __syncthreads();
        }
    }

    // ---------- epilogue: LN2 + residual; also refresh XB with new rows ----------
    #pragma unroll
    for (int mt = 0; mt < 2; mt++)
        #pragma unroll
        for (int r = 0; r < 4; r++) {
            float s = 0.f, q = 0.f;
            #pragma unroll
            for (int pass = 0; pass < 2; pass++)
                #pragma unroll
                for (int nt = 0; nt < 2; nt++) {
                    float v = acc2[pass][mt][nt][r];
                    s += v; q += v * v;
                }
            #pragma unroll
            for (int off = 1; off < 16; off <<= 1) {
                s += __shfl_xor(s, off, 64);
                q += __shfl_xor(q, off, 64);
            }
            if (l16 == 0) {
                stats[w * 32 + mt * 16 + quad * 4 + r] = s;
                stats[128 + w * 32 + mt * 16 + quad * 4 + r] = q;
            }
        }
    __syncthreads();

    #pragma unroll
    for (int mt = 0; mt < 2; mt++) {
        #pragma unroll
        for (int r = 0; r < 4; r++) {
            int rl = mt * 16 + quad * 4 + r;
            float s = stats[rl] + stats[32 + rl] + stats[64 + rl] + stats[96 + rl];
            float q = stats[128 + rl] + stats[160 + rl] + stats[192 + rl] + stats[224 + rl];
            float m = s * (1.f / 256.f);
            float var = q * (1.f / 256.f) - m * m;
            float rs = rsqrtf(var + 1e-5f);
            size_t row = (size_t)(m0 + rl);
            #pragma unroll
            for (int pass = 0; pass < 2; pass++)
                #pragma unroll
                for (int nt = 0; nt < 2; nt++) {
                    int col = pass * 128 + w * 32 + nt * 16 + l16;
                    float y = (acc2[pass][mt][nt][r] - m) * rs * g2[col] + bp[col];
                    float xn = Xin[row * 256 + col] + y;
                    Xout[row * 256 + col] = xn;
                    ushort_t xb16 = f2b(xn);
                    XbfOut[row * 256 + col] = xb16;
                    XB[rl * 256 + (((col >> 3) ^ (rl & 7)) << 3) + (col & 7)] = xb16;
                }
        }
    }

    // ---------- QKV phase: QKVout = XB @ Wqkv(TF), N=768 in 3 chunks ----------
    if (Wqkv) {
        __syncthreads();   // XB refresh visible to all waves
        #pragma unroll
        for (int nc = 0; nc < 3; nc++) {
            f32x4 accq[2][4];
            #pragma unroll
            for (int i = 0; i < 2; i++)
                #pragma unroll
                for (int j = 0; j < 4; j++) accq[i][j] = (f32x4){0.f, 0.f, 0.f, 0.f};

            for (int kb = 0; kb < 256; kb += 64) {
                // Wqkv TF: N=768 (48 n-groups); this chunk = groups nc*16..+15
                #pragma unroll
                for (int q = 0; q < 8; q++) {
                    int s = q * 256 + tid;
                    int kk = s >> 10, p = s & 1023;
                    int rg = p >> 6, gi = p & 63;
                    ASYNC_COPY16(Wqkv + (((size_t)((kb >> 5) + kk) * 48 + nc * 16 + rg) * 512 + gi * 8),
                                 (char*)Bs + s * 16);
                }
                __syncthreads();

                #pragma unroll
                for (int kk = 0; kk < 2; kk++) {
                    short8 af[2], bf[4];
                    #pragma unroll
                    for (int mt = 0; mt < 2; mt++) {
                        int row = mt * 16 + l16;
                        int k = kb + kk * 32 + quad * 8;
                        af[mt] = *(const short8*)&XB[row * 256 + (((k >> 3) ^ (row & 7)) << 3)];
                    }
                    #pragma unroll
                    for (int nt = 0; nt < 4; nt++)
                        bf[nt] = *(const short8*)&Bs[kk * 8192 + (w * 4 + nt) * 512 + (quad * 16 + l16) * 8];
                    #pragma unroll
                    for (int mt = 0; mt < 2; mt++)
                        #pragma unroll
                        for (int nt = 0; nt < 4; nt++)
                            accq[mt][nt] = __builtin_amdgcn_mfma_f32_16x16x32_bf16(
                                af[mt], bf[nt], accq[mt][nt], 0, 0, 0);
                }
                __syncthreads();
            }

            #pragma unroll
            for (int mt = 0; mt < 2; mt++)
                #pragma unroll
                for (int r = 0; r < 4; r++) {
                    int rl = mt * 16 + quad * 4 + r;
                    #pragma unroll
                    for (int nt = 0; nt < 4; nt++) {
                        int col = nc * 256 + w * 64 + nt * 16 + l16;
                        QKVout[(size_t)(m0 + rl) * 768 + col] = f2h(accq[mt][nt][r]);
                    }
                }
        }
    }
}

// ---------------------------------------------------------------------------
// Weight prep: fp32 [K][N] -> bf16 TF-layout (fragment-major transposed);
// q/k/v fused into one TF matrix of N=768. See TF formula at top.
// ---------------------------------------------------------------------------
__global__ __launch_bounds__(256) void wprep_kernel(
    const float* __restrict__ Wq, const float* __restrict__ Wk,
    const float* __restrict__ Wv, const float* __restrict__ Wm,
    const float* __restrict__ W1, const float* __restrict__ W2,
    ushort_t* __restrict__ Wqkvt, ushort_t* __restrict__ Wmt,
    ushort_t* __restrict__ W1t, ushort_t* __restrict__ W2t)
{
    int t = blockIdx.x;
    int layer = t / 640, r = t % 640;
    const float* src; ushort_t* dst;
    int ldsrc, tn, tk, n16, nbase;
    if (r < 192) {
        int grp = r / 64, rr = r % 64; tn = rr / 8; tk = rr % 8;
        src = (grp == 0 ? Wq : grp == 1 ? Wk : Wv) + (size_t)layer * 65536;
        ldsrc = 256;
        dst = Wqkvt + (size_t)layer * 196608;
        n16 = 48; nbase = grp * 256;
    } else if (r < 256) {
        int rr = r - 192; tn = rr / 8; tk = rr % 8;
        src = Wm + (size_t)layer * 65536; ldsrc = 256;
        dst = Wmt + (size_t)layer * 65536; n16 = 16; nbase = 0;
    } else if (r < 512) {
        int rr = r - 256; tn = rr / 16; tk = rr % 16;
        src = W1 + (size_t)layer * 262144; ldsrc = 512;
        dst = W1t + (size_t)layer * 262144; n16 = 32; nbase = 0;
    } else {
        int rr = r - 512; tn = rr / 16; tk = rr % 16;
        src = W2 + (size_t)layer * 131072; ldsrc = 256;
        dst = W2t + (size_t)layer * 131072; n16 = 16; nbase = 0;
    }
    int ln0 = tn * 32, k0 = tk * 32;    // ln0 = local col in src
    __shared__ float tileS[32][33];
    int j = threadIdx.x & 31, i0 = threadIdx.x >> 5;
    #pragma unroll
    for (int p = 0; p < 4; p++) {
        int i = i0 + p * 8;
        tileS[i][j] = src[(size_t)(k0 + i) * ldsrc + ln0 + j];
    }
    __syncthreads();
    #pragma unroll
    for (int p = 0; p < 4; p++) {
        int i = i0 + p * 8;
        int n = nbase + ln0 + i, k = k0 + j;    // value = src[k][n-nbase]
        size_t off = ((size_t)(k >> 5) * n16 + (n >> 4)) * 512
                   + ((k >> 3) & 3) * 128 + (n & 15) * 8 + (k & 7);
        dst[off] = f2b(tileS[j][i]);
    }
}

// init: X fp32 master + Xbf bf16 mirror from feat0/feat1
__global__ __launch_bounds__(256) void init_kernel(
    const float* __restrict__ f0, const float* __restrict__ f1,
    float* __restrict__ X, ushort_t* __restrict__ Xbf)
{
    int idx = blockIdx.x * 256 + threadIdx.x;      // per float4; 1,048,576 total
    size_t e = (size_t)idx * 4;
    float4 v = (e < 2097152) ? *(const float4*)&f0[e] : *(const float4*)&f1[e - 2097152];
    *(float4*)&X[e] = v;
    ushort4_t u = { f2b(v.x), f2b(v.y), f2b(v.z), f2b(v.w) };
    *(ushort4_t*)&Xbf[e] = u;
}

// ---------------------------------------------------------------------------
// Self-attention KV[g,32,32] + Ksum[g,32] over S=4096, f16 in (QKV fused, ld=768).
// ---------------------------------------------------------------------------
__global__ __launch_bounds__(256) void kv_reduce_kernel(
    const ushort_t* __restrict__ QKV,
    const int* __restrict__ mask0, const int* __restrict__ mask1,
    float* __restrict__ KV, float* __restrict__ Ksum)
{
    int g = blockIdx.y;
    int t = g >> 4, b = (g >> 3) & 1, h = g & 7;
    const int* mask = t ? mask1 : mask0;
    int rowbase = t * 8192 + b * 4096;
    int s_begin = blockIdx.x * 256;

    __shared__ float sK[32][32];
    __shared__ float sV[32][32];

    int tid = threadIdx.x;
    int e  = tid & 31;
    int dq = tid >> 5;              // 0..7 ; this thread owns d = dq*4..dq*4+3

    float acc[4] = {0.f, 0.f, 0.f, 0.f};
    float ks[4]  = {0.f, 0.f, 0.f, 0.f};

    for (int s0 = s_begin; s0 < s_begin + 256; s0 += 32) {
        #pragma unroll
        for (int q = 0; q < 2; q++) {
            int idx = tid + q * 256;
            int rl = idx >> 4;
            int part = idx & 15;
            int s = s0 + rl;
            size_t row = (size_t)(rowbase + s);
            float m = mask[b * 4096 + s] ? 1.f : 0.f;
            if (part < 8) {
                half4 u = *(const half4*)&QKV[row * 768 + 256 + h * 32 + part * 4];
                float4 f = { elu1((float)u[0]) * m, elu1((float)u[1]) * m,
                             elu1((float)u[2]) * m, elu1((float)u[3]) * m };
                *(float4*)&sK[rl][part * 4] = f;
            } else {
                half4 u = *(const half4*)&QKV[row * 768 + 512 + h * 32 + (part - 8) * 4];
                float4 f = { (float)u[0] * m, (float)u[1] * m,
                             (float)u[2] * m, (float)u[3] * m };
                *(float4*)&sV[rl][(part - 8) * 4] = f;
            }
        }
        __syncthreads();

        #pragma unroll
        for (int s = 0; s < 32; s++) {
            float4 kq = *(const float4*)&sK[s][dq * 4];
            float vv = sV[s][e];
            acc[0] += kq.x * vv;
            acc[1] += kq.y * vv;
            acc[2] += kq.z * vv;
            acc[3] += kq.w * vv;
            ks[0] += kq.x; ks[1] += kq.y; ks[2] += kq.z; ks[3] += kq.w;
        }
        __syncthreads();
    }

    #pragma unroll
    for (int j = 0; j < 4; j++)
        atomicAdd(&KV[(size_t)g * 1024 + (dq * 4 + j) * 32 + e], acc[j]);
    if (e == 0) {
        #pragma unroll
        for (int j = 0; j < 4; j++)
            atomicAdd(&Ksum[g * 32 + dq * 4 + j], ks[j]);
    }
}

// ---------------------------------------------------------------------------
// R12: attn_apply with KV staged in LDS, 16 rows per block (grid 1024).
// Old version: 16384 blocks each re-reading 32KB of KV from L2 = 512MB
// L2 traffic + 1-wave-deep latency. Now KV+Ksum staged once per block
// (33KB LDS) and reused by 16 rows -> 34MB total. Q broadcast via
// wave-local shfl (each 32-thread head-group lives in one wave; no
// barrier inside the row loop). Math identical to before.
// ---------------------------------------------------------------------------
__global__ __launch_bounds__(256) void attn_apply_kernel(
    const ushort_t* __restrict__ QKV, const float* __restrict__ KV,
    const float* __restrict__ Ksum, ushort_t* __restrict__ MSG)
{
    int rb0 = blockIdx.x * 16;            // 16 rows, all in one (t,b) quadrant
    int gb = (rb0 >> 12) * 8;             // head-group base for this quadrant
    int c = threadIdx.x, h = c >> 5;

    __shared__ float sKV[8192];           // [h][d][e] = 8 x 32 x 32 f32, 32KB
    __shared__ float sKs[256];

    #pragma unroll
    for (int k = 0; k < 8; k++) {
        int i = k * 256 + c;              // float4 index 0..2047
        *(float4*)&sKV[i * 4] = *(const float4*)&KV[(size_t)gb * 1024 + (size_t)i * 4];
    }
    sKs[c] = Ksum[gb * 32 + c];
    __syncthreads();

    float ks = sKs[c];
    int lane = c & 63;
    int gbase = lane & 32;                // this lane's 32-group base within wave

    #pragma unroll
    for (int r = 0; r < 16; r++) {
        int row = rb0 + r;
        float qf = elu1((float)(*(const half_t*)&QKV[(size_t)row * 768 + c]));

        float p = qf * ks;
        #pragma unroll
        for (int off = 16; off; off >>= 1) p += __shfl_xor(p, off, 32);
        float Z = 1.f / (p + 1e-6f);

        float acc = 0.f;
        #pragma unroll
        for (int d = 0; d < 32; d++) {
            float qd = __shfl(qf, gbase + d, 64);     // Q[row][h*32+d], wave-local
            acc += qd * sKV[h * 1024 + d * 32 + (c & 31)];
        }

        MSG[(size_t)row * 256 + c] = f2b(acc * Z);
    }
}

// ---------------------------------------------------------------------------
// Gram table: 12-float stride (10 used + 2 pad for 16B-aligned loads).
// G order: 00,01,02,03,11,12,13,22,23,33.
// ---------------------------------------------------------------------------
__global__ __launch_bounds__(256) void gram_kernel(
    const ushort_t* __restrict__ Xbf, float* __restrict__ Gm)
{
    int a = blockIdx.x * 4 + (threadIdx.x >> 6);
    int lane = threadIdx.x & 63;
    int img = a / 4225;
    int rr = a - img * 4225;
    int ay = rr / 65, ax = rr - ay * 65;
    int xa = ax > 0 ? ax - 1 : 0;
    int xb = ax < 64 ? ax : 63;
    if (ax == 0) xb = 0;
    int ya = ay > 0 ? ay - 1 : 0;
    int yb = ay < 64 ? ay : 63;
    if (ay == 0) yb = 0;

    size_t rbase = (size_t)img * 4096;
    size_t r0 = (rbase + ya * 64 + xa) * 256;
    size_t r1 = (rbase + ya * 64 + xb) * 256;
    size_t r2 = (rbase + yb * 64 + xa) * 256;
    size_t r3 = (rbase + yb * 64 + xb) * 256;

    int c4 = lane * 4;
    ushort4_t u0 = *(const ushort4_t*)&Xbf[r0 + c4];
    ushort4_t u1 = *(const ushort4_t*)&Xbf[r1 + c4];
    ushort4_t u2 = *(const ushort4_t*)&Xbf[r2 + c4];
    ushort4_t u3 = *(const ushort4_t*)&Xbf[r3 + c4];

    float p[10] = {0,0,0,0,0,0,0,0,0,0};
    #pragma unroll
    for (int j = 0; j < 4; j++) {
        float f0 = b2f(u0[j]), f1 = b2f(u1[j]), f2 = b2f(u2[j]), f3 = b2f(u3[j]);
        p[0] += f0 * f0; p[1] += f0 * f1; p[2] += f0 * f2; p[3] += f0 * f3;
        p[4] += f1 * f1; p[5] += f1 * f2; p[6] += f1 * f3;
        p[7] += f2 * f2; p[8] += f2 * f3; p[9] += f3 * f3;
    }
    #pragma unroll
    for (int k = 0; k < 10; k++)
        #pragma unroll
        for (int off = 32; off; off >>= 1) p[k] += __shfl_xor(p[k], off, 64);

    if (lane == 0) {
        #pragma unroll
        for (int k = 0; k < 10; k++) Gm[(size_t)a * 12 + k] = p[k];
    }
}

// ---------------------------------------------------------------------------
// Fused cross attention (S=9): ONE WAVE per query row, 8 ch/lane per half-wave.
// ---------------------------------------------------------------------------
__global__ __launch_bounds__(256) void cross_fused_kernel(
    const ushort_t* __restrict__ QKV, const float* __restrict__ Gm,
    const float* __restrict__ kp0, const float* __restrict__ kp1,
    const int* __restrict__ maskc0, const int* __restrict__ maskc1,
    ushort_t* __restrict__ MSG)
{
    int wv = threadIdx.x >> 6;
    int lane = threadIdx.x & 63;
    int half = lane >> 5;
    int l32 = lane & 31;

    // quadrant swizzle: qd = (blk&7)>>1, within-quadrant = (blk>>3)*2 + (blk&1)
    int blk = blockIdx.x;
    int qd = (blk & 7) >> 1;
    int within = ((blk >> 3) << 1) | (blk & 1);    // 0..1023
    int row = qd * 4096 + within * 4 + wv;

    int t = row >> 13;
    int bl = row & 8191;               // b*4096 + l
    int ts = 1 - t;                    // source image
    const float* kp = ts ? kp1 : kp0;
    const int* mask = (t == 0) ? maskc1 : maskc0;
    int img = ts * 2 + (bl >> 12);
    int rb = img * 4096;               // source row base
    const float* Gimg = Gm + (size_t)img * 50700;   // 4225 * 12

    int c8 = l32 * 8;                  // this lane's 8 channels

    half8 qu = *(const half8*)&QKV[(size_t)row * 768 + c8];
    float qf[8];
    #pragma unroll
    for (int j = 0; j < 8; j++) qf[j] = elu1((float)qu[j]);

    // ---- distributed meta: lane (l32%5) of each half computes ONE sample ----
    float mU0, mU1, mU2, mU3, mSm;
    int mPack;                          // base | dxflag | (dyflag<<1)  (base%4==0)
    {
        int msi = l32 % 5;
        int s9 = half + 2 * msi;        // 0,2,4,6,8 or 1,3,5,7,(9=invalid)
        int valid = (s9 < 9);
        int r = bl * 9 + (valid ? s9 : 0);
        mSm = (valid && mask[r] != 0) ? 1.f : 0.f;

        float2 xy = *(const float2*)&kp[(size_t)r * 2];
        float px = (xy.x - 3.5f) * (63.f / 507.5f);
        float py = (xy.y - 3.5f) * (63.f / 507.5f);
        float fx = floorf(px), fy = floorf(py);
        float wx = px - fx, wy = py - fy;
        int ix = (int)fx, iy = (int)fy;         // -1..63
        int xa = ix > 0 ? ix : 0;
        int xb = ix + 1 > 0 ? (ix + 1 < 63 ? ix + 1 : 63) : 0;
        int ya = iy > 0 ? iy : 0;
        int yb = iy + 1 > 0 ? (iy + 1 < 63 ? iy + 1 : 63) : 0;

        float w0 = (1.f - wy) * (1.f - wx);
        float w1 = (1.f - wy) * wx;
        float w2 = wy * (1.f - wx);
        float w3 = wy * wx;

        const float* G = &Gimg[(size_t)((iy + 1) * 65 + (ix + 1)) * 12];
        float4 ga = *(const float4*)&G[0];   // 00,01,02,03
        float4 gb4 = *(const float4*)&G[4];  // 11,12,13,22
        float2 gc = *(const float2*)&G[8];   // 23,33
        float ss = w0 * w0 * ga.x + w1 * w1 * gb4.x + w2 * w2 * gb4.w + w3 * w3 * gc.y
                 + 2.f * (w0 * w1 * ga.y + w0 * w2 * ga.z + w0 * w3 * ga.w
                        + w1 * w2 * gb4.y + w1 * w3 * gb4.z + w2 * w3 * gc.x);
        float inv = 1.f / (sqrtf(ss) + 1e-8f);
        mU0 = w0 * inv; mU1 = w1 * inv; mU2 = w2 * inv; mU3 = w3 * inv;

        int base = (rb + ya * 64 + xa) * 768;          // multiple of 768 (%4==0)
        mPack = base | (xb - xa) | ((yb - ya) << 1);
    }

    // broadcast: sample si of this half lives in lane (half*32 + si)
    int spack[5];
    float su0[5], su1[5], su2[5], su3[5], sm[5];
    int srcb = half * 32;
    #pragma unroll
    for (int si = 0; si < 5; si++) {
        int src = srcb + si;
        spack[si] = __shfl(mPack, src, 64);
        su0[si] = __shfl(mU0, src, 64);
        su1[si] = __shfl(mU1, src, 64);
        su2[si] = __shfl(mU2, src, 64);
        su3[si] = __shfl(mU3, src, 64);
        sm[si]  = __shfl(mSm, src, 64);
    }

    // ---- main loop: 2-deep double-buffered K/V register pipeline ----
    half8 kR[2][4], vR[2][4];

#define LOADKV(bufi, si_) do { \
        int pk = spack[si_]; \
        int dx = (pk & 1) ? 768 : 0; \
        int dy = (pk & 2) ? 49152 : 0; \
        size_t bK = (size_t)(pk & ~3) + 256 + c8; \
        size_t bV = bK + 256; \
        kR[bufi][0] = *(const half8*)&QKV[bK]; \
        kR[bufi][1] = *(const half8*)&QKV[bK + dx]; \
        kR[bufi][2] = *(const half8*)&QKV[bK + dy]; \
        kR[bufi][3] = *(const half8*)&QKV[bK + dx + dy]; \
        vR[bufi][0] = *(const half8*)&QKV[bV]; \
        vR[bufi][1] = *(const half8*)&QKV[bV + dx]; \
        vR[bufi][2] = *(const half8*)&QKV[bV + dy]; \
        vR[bufi][3] = *(const half8*)&QKV[bV + dx + dy]; \
    } while (0)

    float zsum = 0.f;
    float acc[8] = {0, 0, 0, 0, 0, 0, 0, 0};

    LOADKV(0, 0);
    #pragma unroll
    for (int si = 0; si < 5; si++) {
        int cur = si & 1;
        if (si + 1 < 5) {
            if (cur == 0) LOADKV(1, si + 1);
            else          LOADKV(0, si + 1);
        }
        float u0 = su0[si], u1 = su1[si], u2 = su2[si], u3 = su3[si];
        float p = 0.f;
        #pragma unroll
        for (int j = 0; j < 8; j++) {
            float kc = u0 * (float)kR[cur][0][j] + u1 * (float)kR[cur][1][j]
                     + u2 * (float)kR[cur][2][j] + u3 * (float)kR[cur][3][j];
            p += qf[j] * elu1(kc);
        }
        // head = 32 ch = 4 lanes (group aligned): reduce over 4 lanes
        p += __shfl_xor(p, 1, 64);
        p += __shfl_xor(p, 2, 64);
        p *= sm[si];

        zsum += p;
        float pu0 = p * u0, pu1 = p * u1, pu2 = p * u2, pu3 = p * u3;
        #pragma unroll
        for (int j = 0; j < 8; j++)
            acc[j] += pu0 * (float)vR[cur][0][j] + pu1 * (float)vR[cur][1][j]
                    + pu2 * (float)vR[cur][2][j] + pu3 * (float)vR[cur][3][j];
    }
#undef LOADKV

    // combine the two halves (same channels, disjoint samples)
    zsum += __shfl_xor(zsum, 32, 64);
    #pragma unroll
    for (int j = 0; j < 8; j++) acc[j] += __shfl_xor(acc[j], 32, 64);

    if (half == 0) {
        float Z = 1.f / (zsum + 1e-6f);
        ushort8_t o;
        #pragma unroll
        for (int j = 0; j < 8; j++) o[j] = f2b(acc[j] * Z);
        *(ushort8_t*)&MSG[(size_t)row * 256 + c8] = o;
    }
}

// ---------------------------------------------------------------------------

extern "C" void kernel_launch(void* const* d_in, const int* in_sizes, int n_in,
                              void* d_out, int out_size, void* d_ws, size_t ws_size,
                              hipStream_t stream)
{
    const float* feat0 = (const float*)d_in[0];
    const float* feat1 = (const float*)d_in[1];
    const float* kp0 = (const float*)d_in[2];
    const float* kp1 = (const float*)d_in[3];
    const int* ms0 = (const int*)d_in[4];
    const int* ms1 = (const int*)d_in[5];
    const int* mc0 = (const int*)d_in[6];
    const int* mc1 = (const int*)d_in[7];
    const float* Wq = (const float*)d_in[8];
    const float* Wk = (const float*)d_in[9];
    const float* Wv = (const float*)d_in[10];
    const float* Wm = (const float*)d_in[11];
    const float* W1 = (const float*)d_in[12];
    const float* W2 = (const float*)d_in[13];
    const float* g1 = (const float*)d_in[14];
    const float* b1 = (const float*)d_in[15];
    const float* g2 = (const float*)d_in[16];
    const float* b2 = (const float*)d_in[17];

    // workspace carve (bytes; all offsets 256B-aligned). ~55 MB total.
    char* p = (char*)d_ws;
    float*    X     = (float*)p;            p += 16777216;   // 16384x256 fp32
    ushort_t* Xbf   = (ushort_t*)p;         p += 8388608;    // bf16 mirror
    ushort_t* QKV   = (ushort_t*)p;         p += 25165824;   // 16384x768 f16
    ushort_t* MSG   = (ushort_t*)p;         p += 8388608;    // 16384x256 bf16
    ushort_t* L1bf  = (ushort_t*)p;         p += 8388608;    // (unused after R9 fusion)
    float*    KVb   = (float*)p;            p += 131072;     // 32x1024
    float*    KSb   = (float*)p;            p += 4096;       // 32x32 (KVb+KSb zeroed together)
    float*    Gm    = (float*)p;            p += 811264;     // 4x4225x12 fp32 Gram (padded)
    ushort_t* Wqkvt = (ushort_t*)p;         p += 1572864;    // 4x768x256 bf16 (TF)
    ushort_t* Wmt   = (ushort_t*)p;         p += 524288;     // 4x256x256 (TF)
    ushort_t* W1t   = (ushort_t*)p;         p += 2097152;    // 4x512x512 (TF)
    ushort_t* W2t   = (ushort_t*)p;         p += 1048576;    // 4x256x512 (TF)
    (void)L1bf;

    init_kernel<<<4096, 256, 0, stream>>>(feat0, feat1, X, Xbf);
    wprep_kernel<<<2560, 256, 0, stream>>>(Wq, Wk, Wv, Wm, W1, W2, Wqkvt, Wmt, W1t, W2t);

    // Layer 0 QKV: standalone GEMM (zeroes KVb/KSb for layer 0's kv_reduce).
    gemm_bf16_kernel<<<dim3(6, 128), 256, 0, stream>>>(
        Xbf, 256, Wqkvt, 256, QKV, 768, 256, KVb, 33792 / 4);

    for (int i = 0; i < 4; i++) {
        const ushort_t* Wmt_l   = Wmt   + (size_t)i * 65536;
        const ushort_t* W1t_l   = W1t   + (size_t)i * 262144;
        const ushort_t* W2t_l   = W2t   + (size_t)i * 131072;
        const float* g1_l = g1 + (size_t)i * 256;
        const float* b1_l = b1 + (size_t)i * 256;
        const float* g2_l = g2 + (size_t)i * 256;
        const float* b2_l = b2 + (size_t)i * 256;
        bool is_self = (i == 0 || i == 2);

        if (is_self) {
            kv_reduce_kernel<<<dim3(16, 32), 256, 0, stream>>>(QKV, ms0, ms1, KVb, KSb);
            attn_apply_kernel<<<NROWS / 16, 256, 0, stream>>>(QKV, KVb, KSb, MSG);
        } else {
            gram_kernel<<<4225, 256, 0, stream>>>(Xbf, Gm);
            cross_fused_kernel<<<NROWS / 4, 256, 0, stream>>>(QKV, Gm, kp0, kp1, mc0, mc1, MSG);
        }

        // L1 = ln1(MSG @ Wm); T = tanh([Xbf|L1] @ W1); X += ln2(T @ W2);
        // Xbf = bf16(X); AND QKV for layer i+1 (fused; i==1 also zeroes
        // KVb/KSb for layer 2's kv_reduce).
        float* Xout = (i == 3) ? (float*)d_out : X;
        const ushort_t* Wqkv_next = (i < 3) ? (Wqkvt + (size_t)(i + 1) * 196608) : nullptr;
        float* zb = (i == 1) ? KVb : nullptr;
        mlp_ln_fused_kernel<<<NROWS / 32, 256, 0, stream>>>(
            MSG, Wmt_l, g1_l, b1_l, Xbf, W1t_l, W2t_l, g2_l, b2_l, Xbf, X, Xout,
            Wqkv_next, QKV, zb, 33792 / 4);
    }
}

// Round 13
// 546.287 us; speedup vs baseline: 1.1137x; 1.1137x over previous
//
#include <hip/hip_runtime.h>
#include <cstddef>

// Shapes (hard-coded): B=2, L=4096 (64x64), C=256, H=8, D=32, K=9, scale=8,
// layers: self,cross,self,cross. X rows: 0..8191 feat0 (b0,b1), 8192..16383 feat1.

#define NROWS 16384

typedef unsigned short ushort_t;
typedef __attribute__((ext_vector_type(8))) short short8;
typedef __attribute__((ext_vector_type(4))) float f32x4;
typedef __attribute__((ext_vector_type(4))) unsigned short ushort4_t;
typedef __attribute__((ext_vector_type(8))) unsigned short ushort8_t;
typedef _Float16 half_t;
typedef __attribute__((ext_vector_type(4))) _Float16 half4;
typedef __attribute__((ext_vector_type(8))) _Float16 half8;

__device__ __forceinline__ float b2f(unsigned short u) {
    union { unsigned int i; float f; } v; v.i = (unsigned int)u << 16; return v.f;
}
__device__ __forceinline__ unsigned short f2b(float x) {
    union { float f; unsigned int i; } v; v.f = x;
    unsigned int r = v.i + 0x7fffu + ((v.i >> 16) & 1u);   // RNE
    return (unsigned short)(r >> 16);
}
__device__ __forceinline__ ushort_t f2h(float x) {
    union { half_t h; ushort_t u; } v; v.h = (half_t)x; return v.u;   // v_cvt_f16_f32 RNE
}
// elu(x)+1: for x<=0, elu = exp(x)-1, so elu+1 = exp(x) exactly.
__device__ __forceinline__ float elu1(float x) {
    return x > 0.f ? x + 1.f : __expf(x);
}

#define ASYNC_COPY16(gptr, lptr) \
    __builtin_amdgcn_global_load_lds((const __attribute__((address_space(1))) void*)(gptr), \
                                     (__attribute__((address_space(3))) void*)(lptr), 16, 0, 0)

// ---------------------------------------------------------------------------
// Weights stored FRAGMENT-MAJOR ("TF"): for Wt[N][K] (bf16), granule order =
// [k-panel of 32][n-group of 16][quad = k-granule 0..3][l16 = n&15]:
// offset(n,k) = ((k>>5)*(N>>4) + (n>>4))*512 + ((k>>3)&3)*128 + (n&15)*8 + (k&7).
// Staging is a LINEAR global_load_lds copy; MFMA B-read touches 64 distinct
// consecutive granules.
// ---------------------------------------------------------------------------

// bf16 MFMA GEMM: C[M,N] = A[M,K] @ Wt(TF). 128x128 tile, BK=64. Used ONLY
// for layer 0's QKV projection now (layers 1-3 QKV fused into mlp).
// Side duty: blocks with blockIdx.y==0 zero the KVb/KSb accumulators.
__global__ __launch_bounds__(256) void gemm_bf16_kernel(
    const ushort_t* __restrict__ A0, int lda0,
    const ushort_t* __restrict__ Wt, int ldw,
    ushort_t* __restrict__ C, int ldc, int Kd,
    float* __restrict__ zbuf, int znf4)   // zero zbuf[0..znf4*4) floats
{
    __shared__ ushort_t As[128 * 64];   // 16 KB
    __shared__ ushort_t Bs[128 * 64];   // 16 KB

    int tid = threadIdx.x;
    int m0 = blockIdx.y * 128;
    int n0 = blockIdx.x * 128;
    int lane = tid & 63, w = tid >> 6;
    int wrow = w >> 1, wcol = w & 1;
    int quad = lane >> 4, l16 = lane & 15;

    if (zbuf && blockIdx.y == 0) {
        int nblk = gridDim.x;
        for (int i = blockIdx.x * 256 + tid; i < znf4; i += nblk * 256)
            *(float4*)&zbuf[(size_t)i * 4] = (float4){0.f, 0.f, 0.f, 0.f};
    }

    f32x4 acc[4][4];
    #pragma unroll
    for (int i = 0; i < 4; i++)
        #pragma unroll
        for (int j = 0; j < 4; j++) acc[i][j] = (f32x4){0.f, 0.f, 0.f, 0.f};

    for (int kb = 0; kb < Kd; kb += 64) {
        #pragma unroll
        for (int q = 0; q < 4; q++) {
            int s = q * 256 + tid;
            int kk = s >> 9, p = s & 511;
            int row = p >> 2, c4 = p & 3;
            ASYNC_COPY16(A0 + (size_t)(m0 + row) * lda0 + kb + kk * 32 + c4 * 8,
                         (char*)As + s * 16);
        }
        // B: TF layout, N=768 (48 n-groups). Linear copy of sub-panels.
        #pragma unroll
        for (int q = 0; q < 4; q++) {
            int s = q * 256 + tid;
            int kk = s >> 9, p = s & 511;
            int rg = p >> 6, gi = p & 63;
            ASYNC_COPY16(Wt + (((size_t)((kb >> 5) + kk) * 48 + (n0 >> 4) + rg) * 512 + gi * 8),
                         (char*)Bs + s * 16);
        }
        __syncthreads();

        #pragma unroll
        for (int kk = 0; kk < 2; kk++) {
            short8 af[4], bf[4];
            #pragma unroll
            for (int mt = 0; mt < 4; mt++)
                af[mt] = *(const short8*)&As[kk * 4096 + (wrow * 64 + mt * 16 + l16) * 32 + quad * 8];
            #pragma unroll
            for (int nt = 0; nt < 4; nt++)
                bf[nt] = *(const short8*)&Bs[kk * 4096 + (wcol * 4 + nt) * 512 + (quad * 16 + l16) * 8];
            #pragma unroll
            for (int mt = 0; mt < 4; mt++)
                #pragma unroll
                for (int nt = 0; nt < 4; nt++)
                    acc[mt][nt] = __builtin_amdgcn_mfma_f32_16x16x32_bf16(
                        af[mt], bf[nt], acc[mt][nt], 0, 0, 0);
        }
        __syncthreads();
    }

    #pragma unroll
    for (int mt = 0; mt < 4; mt++) {
        int row = m0 + wrow * 64 + mt * 16 + quad * 4;
        #pragma unroll
        for (int nt = 0; nt < 4; nt++) {
            int col = n0 + wcol * 64 + nt * 16 + l16;
            #pragma unroll
            for (int r = 0; r < 4; r++)
                C[(size_t)(row + r) * ldc + col] = f2h(acc[mt][nt][r]);
        }
    }
}

// ---------------------------------------------------------------------------
// FULLY FUSED ln1 + MLP + ln2 + residual + NEXT-LAYER QKV PROJECTION.
// (see R11 notes) LDS 77K -> 2 blocks/CU.
// ---------------------------------------------------------------------------
__global__ __launch_bounds__(256) void mlp_ln_fused_kernel(
    const ushort_t* __restrict__ MSG, const ushort_t* __restrict__ Wmt,
    const float* __restrict__ g1, const float* __restrict__ b1,
    const ushort_t* __restrict__ Xb,
    const ushort_t* __restrict__ W1t, const ushort_t* __restrict__ W2t,
    const float* __restrict__ g2, const float* __restrict__ bp,
    ushort_t* __restrict__ XbfOut, const float* __restrict__ Xin,
    float* __restrict__ Xout,
    const ushort_t* __restrict__ Wqkv, ushort_t* __restrict__ QKVout,
    float* __restrict__ zbuf, int znf4)
{
    __shared__ ushort_t XB[32 * 256];    // 16K  Xb rows (bf16), swizzled
    __shared__ ushort_t L1s[32 * 256];   // 16K  L1 rows (bf16), swizzled
    __shared__ ushort_t Tnp[32 * 128];   // 8K   current T chunk, swizzled
    __shared__ ushort_t Bs[256 * 64];    // 32K  staging: Wmt / W1t / W2t / Wqkv (TF)
    __shared__ ushort_t As[32 * 64];     // 4K   staging: MSG (phase A)
    __shared__ float stats[256];         // rsum[0:128] rsq[128:256]

    int tid = threadIdx.x;
    int m0 = blockIdx.x * 32;
    int lane = tid & 63, w = tid >> 6;
    int quad = lane >> 4, l16 = lane & 15;

    if (zbuf) {
        for (int ii = blockIdx.x * 256 + tid; ii < znf4; ii += gridDim.x * 256)
            *(float4*)&zbuf[(size_t)ii * 4] = (float4){0.f, 0.f, 0.f, 0.f};
    }

    // ---- XB staging: linear dest, pre-swizzled global source ----
    #pragma unroll
    for (int i = 0; i < 4; i++) {
        int s = i * 256 + tid;
        int row = s >> 5, gp = s & 31;          // dest granule within row
        int gsrc = gp ^ (row & 7);              // source granule
        ASYNC_COPY16(Xb + (size_t)(m0 + row) * 256 + gsrc * 8,
                     (char*)XB + s * 16);
    }

    // ---------- phase A: L1 = LN1(MSG @ Wmt) ----------
    f32x4 accA[2][4];
    #pragma unroll
    for (int i = 0; i < 2; i++)
        #pragma unroll
        for (int j = 0; j < 4; j++) accA[i][j] = (f32x4){0.f, 0.f, 0.f, 0.f};

    for (int kb = 0; kb < 256; kb += 64) {
        {
            int s = tid;
            int kk = s >> 7, p = s & 127;
            ASYNC_COPY16(MSG + (size_t)(m0 + (p >> 2)) * 256 + kb + kk * 32 + (p & 3) * 8,
                         (char*)As + s * 16);
        }
        // Wmt TF: N=256 (16 n-groups)
        #pragma unroll
        for (int q = 0; q < 8; q++) {
            int s = q * 256 + tid;
            int kk = s >> 10, p = s & 1023;
            int rg = p >> 6, gi = p & 63;
            ASYNC_COPY16(Wmt + (((size_t)((kb >> 5) + kk) * 16 + rg) * 512 + gi * 8),
                         (char*)Bs + s * 16);
        }
        __syncthreads();

        #pragma unroll
        for (int kk = 0; kk < 2; kk++) {
            short8 af[2], bf[4];
            #pragma unroll
            for (int mt = 0; mt < 2; mt++)
                af[mt] = *(const short8*)&As[kk * 1024 + (mt * 16 + l16) * 32 + quad * 8];
            #pragma unroll
            for (int nt = 0; nt < 4; nt++)
                bf[nt] = *(const short8*)&Bs[kk * 8192 + (w * 4 + nt) * 512 + (quad * 16 + l16) * 8];
            #pragma unroll
            for (int mt = 0; mt < 2; mt++)
                #pragma unroll
                for (int nt = 0; nt < 4; nt++)
                    accA[mt][nt] = __builtin_amdgcn_mfma_f32_16x16x32_bf16(
                        af[mt], bf[nt], accA[mt][nt], 0, 0, 0);
        }
        __syncthreads();
    }

    // LN1 stats + write L1s (swizzled)
    #pragma unroll
    for (int mt = 0; mt < 2; mt++)
        #pragma unroll
        for (int r = 0; r < 4; r++) {
            float s = 0.f, q = 0.f;
            #pragma unroll
            for (int nt = 0; nt < 4; nt++) {
                float v = accA[mt][nt][r];
                s += v; q += v * v;
            }
            #pragma unroll
            for (int off = 1; off < 16; off <<= 1) {
                s += __shfl_xor(s, off, 64);
                q += __shfl_xor(q, off, 64);
            }
            if (l16 == 0) {
                stats[w * 32 + mt * 16 + quad * 4 + r] = s;
                stats[128 + w * 32 + mt * 16 + quad * 4 + r] = q;
            }
        }
    __syncthreads();

    #pragma unroll
    for (int mt = 0; mt < 2; mt++) {
        #pragma unroll
        for (int r = 0; r < 4; r++) {
            int rl = mt * 16 + quad * 4 + r;
            float s = stats[rl] + stats[32 + rl] + stats[64 + rl] + stats[96 + rl];
            float q = stats[128 + rl] + stats[160 + rl] + stats[192 + rl] + stats[224 + rl];
            float m = s * (1.f / 256.f);
            float var = q * (1.f / 256.f) - m * m;
            float rs = rsqrtf(var + 1e-5f);
            #pragma unroll
            for (int nt = 0; nt < 4; nt++) {
                int col = w * 64 + nt * 16 + l16;
                float y = (accA[mt][nt][r] - m) * rs * g1[col] + b1[col];
                L1s[rl * 256 + (((col >> 3) ^ (rl & 7)) << 3) + (col & 7)] = f2b(y);
            }
        }
    }
    __syncthreads();

    // ---------- np loop: stage1 (Tnp) then stage2 partial-accumulate ----------
    f32x4 acc2[2][2][2];
    #pragma unroll
    for (int a = 0; a < 2; a++)
        #pragma unroll
        for (int i = 0; i < 2; i++)
            #pragma unroll
            for (int j = 0; j < 2; j++) acc2[a][i][j] = (f32x4){0.f, 0.f, 0.f, 0.f};

    #pragma unroll
    for (int np = 0; np < 4; np++) {
        // ----- stage1: Tnp = tanh([XB|L1s] @ W1t[np*128 .. +128]) -----
        f32x4 acc1[2][2];
        #pragma unroll
        for (int i = 0; i < 2; i++)
            #pragma unroll
            for (int j = 0; j < 2; j++) acc1[i][j] = (f32x4){0.f, 0.f, 0.f, 0.f};

        #pragma unroll
        for (int kb = 0; kb < 512; kb += 128) {
            // W1t TF: N=512 (32 n-groups); rows np*8..np*8+7
            #pragma unroll
            for (int q = 0; q < 8; q++) {
                int s = q * 256 + tid;
                int kk = s >> 9, p = s & 511;
                int rg = p >> 6, gi = p & 63;
                ASYNC_COPY16(W1t + (((size_t)((kb >> 5) + kk) * 32 + np * 8 + rg) * 512 + gi * 8),
                             (char*)Bs + s * 16);
            }
            __syncthreads();

            #pragma unroll
            for (int kk = 0; kk < 4; kk++) {
                short8 af[2], bfr[2];
                #pragma unroll
                for (int mt = 0; mt < 2; mt++) {
                    int row = mt * 16 + l16;
                    int k = kb + kk * 32 + quad * 8;
                    if (k < 256)
                        af[mt] = *(const short8*)&XB[row * 256 + (((k >> 3) ^ (row & 7)) << 3)];
                    else
                        af[mt] = *(const short8*)&L1s[row * 256 + ((((k - 256) >> 3) ^ (row & 7)) << 3)];
                }
                #pragma unroll
                for (int nt = 0; nt < 2; nt++)
                    bfr[nt] = *(const short8*)&Bs[kk * 4096 + (w * 2 + nt) * 512 + (quad * 16 + l16) * 8];
                #pragma unroll
                for (int mt = 0; mt < 2; mt++)
                    #pragma unroll
                    for (int nt = 0; nt < 2; nt++)
                        acc1[mt][nt] = __builtin_amdgcn_mfma_f32_16x16x32_bf16(
                            af[mt], bfr[nt], acc1[mt][nt], 0, 0, 0);
            }
            __syncthreads();
        }

        // tanh -> Tnp (swizzled)
        #pragma unroll
        for (int mt = 0; mt < 2; mt++)
            #pragma unroll
            for (int nt = 0; nt < 2; nt++)
                #pragma unroll
                for (int r = 0; r < 4; r++) {
                    int trow = mt * 16 + quad * 4 + r;
                    int c = w * 32 + nt * 16 + l16;     // local col 0..127
                    Tnp[trow * 128 + (((c >> 3) ^ (trow & 7)) << 3) + (c & 7)] =
                        f2b(tanhf(acc1[mt][nt][r]));
                }
        __syncthreads();

        // ----- stage2 partial: acc2 += Tnp @ W2t[k = np*128 .. +128] -----
        #pragma unroll
        for (int kb2 = 0; kb2 < 128; kb2 += 64) {
            // W2t TF: N=256 (16 n-groups); k-panels np*4 + kb2/32 + kk
            #pragma unroll
            for (int q = 0; q < 8; q++) {
                int s = q * 256 + tid;
                int kk = s >> 10, p = s & 1023;
                int rg = p >> 6, gi = p & 63;
                ASYNC_COPY16(W2t + (((size_t)(np * 4 + (kb2 >> 5) + kk) * 16 + rg) * 512 + gi * 8),
                             (char*)Bs + s * 16);
            }
            __syncthreads();

            #pragma unroll
            for (int kk = 0; kk < 2; kk++) {
                short8 af[2];
                #pragma unroll
                for (int mt = 0; mt < 2; mt++) {
                    int row = mt * 16 + l16;
                    int klocal = kb2 + kk * 32 + quad * 8;
                    af[mt] = *(const short8*)&Tnp[row * 128 + (((klocal >> 3) ^ (row & 7)) << 3)];
                }
                #pragma unroll
                for (int pass = 0; pass < 2; pass++)
                    #pragma unroll
                    for (int nt = 0; nt < 2; nt++) {
                        short8 bfr = *(const short8*)&Bs[kk * 8192 +
                            (pass * 8 + w * 2 + nt) * 512 + (quad * 16 + l16) * 8];
                        #pragma unroll
                        for (int mt = 0; mt < 2; mt++)
                            acc2[pass][mt][nt] = __builtin_amdgcn_mfma_f32_16x16x32_bf16(
                                af[mt], bfr, acc2[pass][mt][nt], 0, 0, 0);
                    }
            }
            __syncthreads();
        }
    }

    // ---------- epilogue: LN2 + residual; also refresh XB with new rows ----------
    #pragma unroll
    for (int mt = 0; mt < 2; mt++)
        #pragma unroll
        for (int r = 0; r < 4; r++) {
            float s = 0.f, q = 0.f;
            #pragma unroll
            for (int pass = 0; pass < 2; pass++)
                #pragma unroll
                for (int nt = 0; nt < 2; nt++) {
                    float v = acc2[pass][mt][nt][r];
                    s += v; q += v * v;
                }
            #pragma unroll
            for (int off = 1; off < 16; off <<= 1) {
                s += __shfl_xor(s, off, 64);
                q += __shfl_xor(q, off, 64);
            }
            if (l16 == 0) {
                stats[w * 32 + mt * 16 + quad * 4 + r] = s;
                stats[128 + w * 32 + mt * 16 + quad * 4 + r] = q;
            }
        }
    __syncthreads();

    #pragma unroll
    for (int mt = 0; mt < 2; mt++) {
        #pragma unroll
        for (int r = 0; r < 4; r++) {
            int rl = mt * 16 + quad * 4 + r;
            float s = stats[rl] + stats[32 + rl] + stats[64 + rl] + stats[96 + rl];
            float q = stats[128 + rl] + stats[160 + rl] + stats[192 + rl] + stats[224 + rl];
            float m = s * (1.f / 256.f);
            float var = q * (1.f / 256.f) - m * m;
            float rs = rsqrtf(var + 1e-5f);
            size_t row = (size_t)(m0 + rl);
            #pragma unroll
            for (int pass = 0; pass < 2; pass++)
                #pragma unroll
                for (int nt = 0; nt < 2; nt++) {
                    int col = pass * 128 + w * 32 + nt * 16 + l16;
                    float y = (acc2[pass][mt][nt][r] - m) * rs * g2[col] + bp[col];
                    float xn = Xin[row * 256 + col] + y;
                    Xout[row * 256 + col] = xn;
                    ushort_t xb16 = f2b(xn);
                    XbfOut[row * 256 + col] = xb16;
                    XB[rl * 256 + (((col >> 3) ^ (rl & 7)) << 3) + (col & 7)] = xb16;
                }
        }
    }

    // ---------- QKV phase: QKVout = XB @ Wqkv(TF), N=768 in 3 chunks ----------
    if (Wqkv) {
        __syncthreads();   // XB refresh visible to all waves
        #pragma unroll
        for (int nc = 0; nc < 3; nc++) {
            f32x4 accq[2][4];
            #pragma unroll
            for (int i = 0; i < 2; i++)
                #pragma unroll
                for (int j = 0; j < 4; j++) accq[i][j] = (f32x4){0.f, 0.f, 0.f, 0.f};

            for (int kb = 0; kb < 256; kb += 64) {
                // Wqkv TF: N=768 (48 n-groups); this chunk = groups nc*16..+15
                #pragma unroll
                for (int q = 0; q < 8; q++) {
                    int s = q * 256 + tid;
                    int kk = s >> 10, p = s & 1023;
                    int rg = p >> 6, gi = p & 63;
                    ASYNC_COPY16(Wqkv + (((size_t)((kb >> 5) + kk) * 48 + nc * 16 + rg) * 512 + gi * 8),
                                 (char*)Bs + s * 16);
                }
                __syncthreads();

                #pragma unroll
                for (int kk = 0; kk < 2; kk++) {
                    short8 af[2], bf[4];
                    #pragma unroll
                    for (int mt = 0; mt < 2; mt++) {
                        int row = mt * 16 + l16;
                        int k = kb + kk * 32 + quad * 8;
                        af[mt] = *(const short8*)&XB[row * 256 + (((k >> 3) ^ (row & 7)) << 3)];
                    }
                    #pragma unroll
                    for (int nt = 0; nt < 4; nt++)
                        bf[nt] = *(const short8*)&Bs[kk * 8192 + (w * 4 + nt) * 512 + (quad * 16 + l16) * 8];
                    #pragma unroll
                    for (int mt = 0; mt < 2; mt++)
                        #pragma unroll
                        for (int nt = 0; nt < 4; nt++)
                            accq[mt][nt] = __builtin_amdgcn_mfma_f32_16x16x32_bf16(
                                af[mt], bf[nt], accq[mt][nt], 0, 0, 0);
                }
                __syncthreads();
            }

            #pragma unroll
            for (int mt = 0; mt < 2; mt++)
                #pragma unroll
                for (int r = 0; r < 4; r++) {
                    int rl = mt * 16 + quad * 4 + r;
                    #pragma unroll
                    for (int nt = 0; nt < 4; nt++) {
                        int col = nc * 256 + w * 64 + nt * 16 + l16;
                        QKVout[(size_t)(m0 + rl) * 768 + col] = f2h(accq[mt][nt][r]);
                    }
                }
        }
    }
}

// ---------------------------------------------------------------------------
// Weight prep: fp32 [K][N] -> bf16 TF-layout (fragment-major transposed);
// q/k/v fused into one TF matrix of N=768. See TF formula at top.
// ---------------------------------------------------------------------------
__global__ __launch_bounds__(256) void wprep_kernel(
    const float* __restrict__ Wq, const float* __restrict__ Wk,
    const float* __restrict__ Wv, const float* __restrict__ Wm,
    const float* __restrict__ W1, const float* __restrict__ W2,
    ushort_t* __restrict__ Wqkvt, ushort_t* __restrict__ Wmt,
    ushort_t* __restrict__ W1t, ushort_t* __restrict__ W2t)
{
    int t = blockIdx.x;
    int layer = t / 640, r = t % 640;
    const float* src; ushort_t* dst;
    int ldsrc, tn, tk, n16, nbase;
    if (r < 192) {
        int grp = r / 64, rr = r % 64; tn = rr / 8; tk = rr % 8;
        src = (grp == 0 ? Wq : grp == 1 ? Wk : Wv) + (size_t)layer * 65536;
        ldsrc = 256;
        dst = Wqkvt + (size_t)layer * 196608;
        n16 = 48; nbase = grp * 256;
    } else if (r < 256) {
        int rr = r - 192; tn = rr / 8; tk = rr % 8;
        src = Wm + (size_t)layer * 65536; ldsrc = 256;
        dst = Wmt + (size_t)layer * 65536; n16 = 16; nbase = 0;
    } else if (r < 512) {
        int rr = r - 256; tn = rr / 16; tk = rr % 16;
        src = W1 + (size_t)layer * 262144; ldsrc = 512;
        dst = W1t + (size_t)layer * 262144; n16 = 32; nbase = 0;
    } else {
        int rr = r - 512; tn = rr / 16; tk = rr % 16;
        src = W2 + (size_t)layer * 131072; ldsrc = 256;
        dst = W2t + (size_t)layer * 131072; n16 = 16; nbase = 0;
    }
    int ln0 = tn * 32, k0 = tk * 32;    // ln0 = local col in src
    __shared__ float tileS[32][33];
    int j = threadIdx.x & 31, i0 = threadIdx.x >> 5;
    #pragma unroll
    for (int p = 0; p < 4; p++) {
        int i = i0 + p * 8;
        tileS[i][j] = src[(size_t)(k0 + i) * ldsrc + ln0 + j];
    }
    __syncthreads();
    #pragma unroll
    for (int p = 0; p < 4; p++) {
        int i = i0 + p * 8;
        int n = nbase + ln0 + i, k = k0 + j;    // value = src[k][n-nbase]
        size_t off = ((size_t)(k >> 5) * n16 + (n >> 4)) * 512
                   + ((k >> 3) & 3) * 128 + (n & 15) * 8 + (k & 7);
        dst[off] = f2b(tileS[j][i]);
    }
}

// init: X fp32 master + Xbf bf16 mirror from feat0/feat1
__global__ __launch_bounds__(256) void init_kernel(
    const float* __restrict__ f0, const float* __restrict__ f1,
    float* __restrict__ X, ushort_t* __restrict__ Xbf)
{
    int idx = blockIdx.x * 256 + threadIdx.x;      // per float4; 1,048,576 total
    size_t e = (size_t)idx * 4;
    float4 v = (e < 2097152) ? *(const float4*)&f0[e] : *(const float4*)&f1[e - 2097152];
    *(float4*)&X[e] = v;
    ushort4_t u = { f2b(v.x), f2b(v.y), f2b(v.z), f2b(v.w) };
    *(ushort4_t*)&Xbf[e] = u;
}

// ---------------------------------------------------------------------------
// Self-attention KV[g,32,32] + Ksum[g,32] over S=4096, f16 in (QKV fused, ld=768).
// ---------------------------------------------------------------------------
__global__ __launch_bounds__(256) void kv_reduce_kernel(
    const ushort_t* __restrict__ QKV,
    const int* __restrict__ mask0, const int* __restrict__ mask1,
    float* __restrict__ KV, float* __restrict__ Ksum)
{
    int g = blockIdx.y;
    int t = g >> 4, b = (g >> 3) & 1, h = g & 7;
    const int* mask = t ? mask1 : mask0;
    int rowbase = t * 8192 + b * 4096;
    int s_begin = blockIdx.x * 256;

    __shared__ float sK[32][32];
    __shared__ float sV[32][32];

    int tid = threadIdx.x;
    int e  = tid & 31;
    int dq = tid >> 5;              // 0..7 ; this thread owns d = dq*4..dq*4+3

    float acc[4] = {0.f, 0.f, 0.f, 0.f};
    float ks[4]  = {0.f, 0.f, 0.f, 0.f};

    for (int s0 = s_begin; s0 < s_begin + 256; s0 += 32) {
        #pragma unroll
        for (int q = 0; q < 2; q++) {
            int idx = tid + q * 256;
            int rl = idx >> 4;
            int part = idx & 15;
            int s = s0 + rl;
            size_t row = (size_t)(rowbase + s);
            float m = mask[b * 4096 + s] ? 1.f : 0.f;
            if (part < 8) {
                half4 u = *(const half4*)&QKV[row * 768 + 256 + h * 32 + part * 4];
                float4 f = { elu1((float)u[0]) * m, elu1((float)u[1]) * m,
                             elu1((float)u[2]) * m, elu1((float)u[3]) * m };
                *(float4*)&sK[rl][part * 4] = f;
            } else {
                half4 u = *(const half4*)&QKV[row * 768 + 512 + h * 32 + (part - 8) * 4];
                float4 f = { (float)u[0] * m, (float)u[1] * m,
                             (float)u[2] * m, (float)u[3] * m };
                *(float4*)&sV[rl][(part - 8) * 4] = f;
            }
        }
        __syncthreads();

        #pragma unroll
        for (int s = 0; s < 32; s++) {
            float4 kq = *(const float4*)&sK[s][dq * 4];
            float vv = sV[s][e];
            acc[0] += kq.x * vv;
            acc[1] += kq.y * vv;
            acc[2] += kq.z * vv;
            acc[3] += kq.w * vv;
            ks[0] += kq.x; ks[1] += kq.y; ks[2] += kq.z; ks[3] += kq.w;
        }
        __syncthreads();
    }

    #pragma unroll
    for (int j = 0; j < 4; j++)
        atomicAdd(&KV[(size_t)g * 1024 + (dq * 4 + j) * 32 + e], acc[j]);
    if (e == 0) {
        #pragma unroll
        for (int j = 0; j < 4; j++)
            atomicAdd(&Ksum[g * 32 + dq * 4 + j], ks[j]);
    }
}

// attn_apply (R11 version, reverted from R12): one row per block, 16384
// blocks. KV (32KB/quadrant) is L1-resident; the R12 16-rows-per-block
// LDS-staged variant traded away TLP for locality the cache already
// provided and regressed +26us/dispatch.
__global__ __launch_bounds__(256) void attn_apply_kernel(
    const ushort_t* __restrict__ QKV, const float* __restrict__ KV,
    const float* __restrict__ Ksum, ushort_t* __restrict__ MSG)
{
    int row = blockIdx.x;
    int t = row >> 13, bb = (row >> 12) & 1;
    int gb = (t * 2 + bb) * 8;
    int c = threadIdx.x, h = c >> 5, e = c & 31;
    int g = gb + h;

    __shared__ float sQ[256];
    float qf = elu1((float)(*(const half_t*)&QKV[(size_t)row * 768 + c]));
    sQ[c] = qf;
    __syncthreads();

    float p = qf * Ksum[g * 32 + e];
    #pragma unroll
    for (int off = 16; off; off >>= 1) p += __shfl_xor(p, off, 32);
    float Z = 1.f / (p + 1e-6f);

    float acc = 0.f;
    #pragma unroll
    for (int d = 0; d < 32; d++)
        acc += sQ[h * 32 + d] * KV[(size_t)g * 1024 + d * 32 + e];

    MSG[(size_t)row * 256 + c] = f2b(acc * Z);
}

// ---------------------------------------------------------------------------
// Gram table: 12-float stride (10 used + 2 pad for 16B-aligned loads).
// G order: 00,01,02,03,11,12,13,22,23,33.
// ---------------------------------------------------------------------------
__global__ __launch_bounds__(256) void gram_kernel(
    const ushort_t* __restrict__ Xbf, float* __restrict__ Gm)
{
    int a = blockIdx.x * 4 + (threadIdx.x >> 6);
    int lane = threadIdx.x & 63;
    int img = a / 4225;
    int rr = a - img * 4225;
    int ay = rr / 65, ax = rr - ay * 65;
    int xa = ax > 0 ? ax - 1 : 0;
    int xb = ax < 64 ? ax : 63;
    if (ax == 0) xb = 0;
    int ya = ay > 0 ? ay - 1 : 0;
    int yb = ay < 64 ? ay : 63;
    if (ay == 0) yb = 0;

    size_t rbase = (size_t)img * 4096;
    size_t r0 = (rbase + ya * 64 + xa) * 256;
    size_t r1 = (rbase + ya * 64 + xb) * 256;
    size_t r2 = (rbase + yb * 64 + xa) * 256;
    size_t r3 = (rbase + yb * 64 + xb) * 256;

    int c4 = lane * 4;
    ushort4_t u0 = *(const ushort4_t*)&Xbf[r0 + c4];
    ushort4_t u1 = *(const ushort4_t*)&Xbf[r1 + c4];
    ushort4_t u2 = *(const ushort4_t*)&Xbf[r2 + c4];
    ushort4_t u3 = *(const ushort4_t*)&Xbf[r3 + c4];

    float p[10] = {0,0,0,0,0,0,0,0,0,0};
    #pragma unroll
    for (int j = 0; j < 4; j++) {
        float f0 = b2f(u0[j]), f1 = b2f(u1[j]), f2 = b2f(u2[j]), f3 = b2f(u3[j]);
        p[0] += f0 * f0; p[1] += f0 * f1; p[2] += f0 * f2; p[3] += f0 * f3;
        p[4] += f1 * f1; p[5] += f1 * f2; p[6] += f1 * f3;
        p[7] += f2 * f2; p[8] += f2 * f3; p[9] += f3 * f3;
    }
    #pragma unroll
    for (int k = 0; k < 10; k++)
        #pragma unroll
        for (int off = 32; off; off >>= 1) p[k] += __shfl_xor(p[k], off, 64);

    if (lane == 0) {
        #pragma unroll
        for (int k = 0; k < 10; k++) Gm[(size_t)a * 12 + k] = p[k];
    }
}

// ---------------------------------------------------------------------------
// Fused cross attention (S=9): ONE WAVE per query row, 8 ch/lane per half-wave.
// ---------------------------------------------------------------------------
__global__ __launch_bounds__(256) void cross_fused_kernel(
    const ushort_t* __restrict__ QKV, const float* __restrict__ Gm,
    const float* __restrict__ kp0, const float* __restrict__ kp1,
    const int* __restrict__ maskc0, const int* __restrict__ maskc1,
    ushort_t* __restrict__ MSG)
{
    int wv = threadIdx.x >> 6;
    int lane = threadIdx.x & 63;
    int half = lane >> 5;
    int l32 = lane & 31;

    // quadrant swizzle: qd = (blk&7)>>1, within-quadrant = (blk>>3)*2 + (blk&1)
    int blk = blockIdx.x;
    int qd = (blk & 7) >> 1;
    int within = ((blk >> 3) << 1) | (blk & 1);    // 0..1023
    int row = qd * 4096 + within * 4 + wv;

    int t = row >> 13;
    int bl = row & 8191;               // b*4096 + l
    int ts = 1 - t;                    // source image
    const float* kp = ts ? kp1 : kp0;
    const int* mask = (t == 0) ? maskc1 : maskc0;
    int img = ts * 2 + (bl >> 12);
    int rb = img * 4096;               // source row base
    const float* Gimg = Gm + (size_t)img * 50700;   // 4225 * 12

    int c8 = l32 * 8;                  // this lane's 8 channels

    half8 qu = *(const half8*)&QKV[(size_t)row * 768 + c8];
    float qf[8];
    #pragma unroll
    for (int j = 0; j < 8; j++) qf[j] = elu1((float)qu[j]);

    // ---- distributed meta: lane (l32%5) of each half computes ONE sample ----
    float mU0, mU1, mU2, mU3, mSm;
    int mPack;                          // base | dxflag | (dyflag<<1)  (base%4==0)
    {
        int msi = l32 % 5;
        int s9 = half + 2 * msi;        // 0,2,4,6,8 or 1,3,5,7,(9=invalid)
        int valid = (s9 < 9);
        int r = bl * 9 + (valid ? s9 : 0);
        mSm = (valid && mask[r] != 0) ? 1.f : 0.f;

        float2 xy = *(const float2*)&kp[(size_t)r * 2];
        float px = (xy.x - 3.5f) * (63.f / 507.5f);
        float py = (xy.y - 3.5f) * (63.f / 507.5f);
        float fx = floorf(px), fy = floorf(py);
        float wx = px - fx, wy = py - fy;
        int ix = (int)fx, iy = (int)fy;         // -1..63
        int xa = ix > 0 ? ix : 0;
        int xb = ix + 1 > 0 ? (ix + 1 < 63 ? ix + 1 : 63) : 0;
        int ya = iy > 0 ? iy : 0;
        int yb = iy + 1 > 0 ? (iy + 1 < 63 ? iy + 1 : 63) : 0;

        float w0 = (1.f - wy) * (1.f - wx);
        float w1 = (1.f - wy) * wx;
        float w2 = wy * (1.f - wx);
        float w3 = wy * wx;

        const float* G = &Gimg[(size_t)((iy + 1) * 65 + (ix + 1)) * 12];
        float4 ga = *(const float4*)&G[0];   // 00,01,02,03
        float4 gb4 = *(const float4*)&G[4];  // 11,12,13,22
        float2 gc = *(const float2*)&G[8];   // 23,33
        float ss = w0 * w0 * ga.x + w1 * w1 * gb4.x + w2 * w2 * gb4.w + w3 * w3 * gc.y
                 + 2.f * (w0 * w1 * ga.y + w0 * w2 * ga.z + w0 * w3 * ga.w
                        + w1 * w2 * gb4.y + w1 * w3 * gb4.z + w2 * w3 * gc.x);
        float inv = 1.f / (sqrtf(ss) + 1e-8f);
        mU0 = w0 * inv; mU1 = w1 * inv; mU2 = w2 * inv; mU3 = w3 * inv;

        int base = (rb + ya * 64 + xa) * 768;          // multiple of 768 (%4==0)
        mPack = base | (xb - xa) | ((yb - ya) << 1);
    }

    // broadcast: sample si of this half lives in lane (half*32 + si)
    int spack[5];
    float su0[5], su1[5], su2[5], su3[5], sm[5];
    int srcb = half * 32;
    #pragma unroll
    for (int si = 0; si < 5; si++) {
        int src = srcb + si;
        spack[si] = __shfl(mPack, src, 64);
        su0[si] = __shfl(mU0, src, 64);
        su1[si] = __shfl(mU1, src, 64);
        su2[si] = __shfl(mU2, src, 64);
        su3[si] = __shfl(mU3, src, 64);
        sm[si]  = __shfl(mSm, src, 64);
    }

    // ---- main loop: 2-deep double-buffered K/V register pipeline ----
    half8 kR[2][4], vR[2][4];

#define LOADKV(bufi, si_) do { \
        int pk = spack[si_]; \
        int dx = (pk & 1) ? 768 : 0; \
        int dy = (pk & 2) ? 49152 : 0; \
        size_t bK = (size_t)(pk & ~3) + 256 + c8; \
        size_t bV = bK + 256; \
        kR[bufi][0] = *(const half8*)&QKV[bK]; \
        kR[bufi][1] = *(const half8*)&QKV[bK + dx]; \
        kR[bufi][2] = *(const half8*)&QKV[bK + dy]; \
        kR[bufi][3] = *(const half8*)&QKV[bK + dx + dy]; \
        vR[bufi][0] = *(const half8*)&QKV[bV]; \
        vR[bufi][1] = *(const half8*)&QKV[bV + dx]; \
        vR[bufi][2] = *(const half8*)&QKV[bV + dy]; \
        vR[bufi][3] = *(const half8*)&QKV[bV + dx + dy]; \
    } while (0)

    float zsum = 0.f;
    float acc[8] = {0, 0, 0, 0, 0, 0, 0, 0};

    LOADKV(0, 0);
    #pragma unroll
    for (int si = 0; si < 5; si++) {
        int cur = si & 1;
        if (si + 1 < 5) {
            if (cur == 0) LOADKV(1, si + 1);
            else          LOADKV(0, si + 1);
        }
        float u0 = su0[si], u1 = su1[si], u2 = su2[si], u3 = su3[si];
        float p = 0.f;
        #pragma unroll
        for (int j = 0; j < 8; j++) {
            float kc = u0 * (float)kR[cur][0][j] + u1 * (float)kR[cur][1][j]
                     + u2 * (float)kR[cur][2][j] + u3 * (float)kR[cur][3][j];
            p += qf[j] * elu1(kc);
        }
        // head = 32 ch = 4 lanes (group aligned): reduce over 4 lanes
        p += __shfl_xor(p, 1, 64);
        p += __shfl_xor(p, 2, 64);
        p *= sm[si];

        zsum += p;
        float pu0 = p * u0, pu1 = p * u1, pu2 = p * u2, pu3 = p * u3;
        #pragma unroll
        for (int j = 0; j < 8; j++)
            acc[j] += pu0 * (float)vR[cur][0][j] + pu1 * (float)vR[cur][1][j]
                    + pu2 * (float)vR[cur][2][j] + pu3 * (float)vR[cur][3][j];
    }
#undef LOADKV

    // combine the two halves (same channels, disjoint samples)
    zsum += __shfl_xor(zsum, 32, 64);
    #pragma unroll
    for (int j = 0; j < 8; j++) acc[j] += __shfl_xor(acc[j], 32, 64);

    if (half == 0) {
        float Z = 1.f / (zsum + 1e-6f);
        ushort8_t o;
        #pragma unroll
        for (int j = 0; j < 8; j++) o[j] = f2b(acc[j] * Z);
        *(ushort8_t*)&MSG[(size_t)row * 256 + c8] = o;
    }
}

// ---------------------------------------------------------------------------

extern "C" void kernel_launch(void* const* d_in, const int* in_sizes, int n_in,
                              void* d_out, int out_size, void* d_ws, size_t ws_size,
                              hipStream_t stream)
{
    const float* feat0 = (const float*)d_in[0];
    const float* feat1 = (const float*)d_in[1];
    const float* kp0 = (const float*)d_in[2];
    const float* kp1 = (const float*)d_in[3];
    const int* ms0 = (const int*)d_in[4];
    const int* ms1 = (const int*)d_in[5];
    const int* mc0 = (const int*)d_in[6];
    const int* mc1 = (const int*)d_in[7];
    const float* Wq = (const float*)d_in[8];
    const float* Wk = (const float*)d_in[9];
    const float* Wv = (const float*)d_in[10];
    const float* Wm = (const float*)d_in[11];
    const float* W1 = (const float*)d_in[12];
    const float* W2 = (const float*)d_in[13];
    const float* g1 = (const float*)d_in[14];
    const float* b1 = (const float*)d_in[15];
    const float* g2 = (const float*)d_in[16];
    const float* b2 = (const float*)d_in[17];

    // workspace carve (bytes; all offsets 256B-aligned). ~55 MB total.
    char* p = (char*)d_ws;
    float*    X     = (float*)p;            p += 16777216;   // 16384x256 fp32
    ushort_t* Xbf   = (ushort_t*)p;         p += 8388608;    // bf16 mirror
    ushort_t* QKV   = (ushort_t*)p;         p += 25165824;   // 16384x768 f16
    ushort_t* MSG   = (ushort_t*)p;         p += 8388608;    // 16384x256 bf16
    ushort_t* L1bf  = (ushort_t*)p;         p += 8388608;    // (unused after R9 fusion)
    float*    KVb   = (float*)p;            p += 131072;     // 32x1024
    float*    KSb   = (float*)p;            p += 4096;       // 32x32 (KVb+KSb zeroed together)
    float*    Gm    = (float*)p;            p += 811264;     // 4x4225x12 fp32 Gram (padded)
    ushort_t* Wqkvt = (ushort_t*)p;         p += 1572864;    // 4x768x256 bf16 (TF)
    ushort_t* Wmt   = (ushort_t*)p;         p += 524288;     // 4x256x256 (TF)
    ushort_t* W1t   = (ushort_t*)p;         p += 2097152;    // 4x512x512 (TF)
    ushort_t* W2t   = (ushort_t*)p;         p += 1048576;    // 4x256x512 (TF)
    (void)L1bf;

    init_kernel<<<4096, 256, 0, stream>>>(feat0, feat1, X, Xbf);
    wprep_kernel<<<2560, 256, 0, stream>>>(Wq, Wk, Wv, Wm, W1, W2, Wqkvt, Wmt, W1t, W2t);

    // Layer 0 QKV: standalone GEMM (zeroes KVb/KSb for layer 0's kv_reduce).
    gemm_bf16_kernel<<<dim3(6, 128), 256, 0, stream>>>(
        Xbf, 256, Wqkvt, 256, QKV, 768, 256, KVb, 33792 / 4);

    for (int i = 0; i < 4; i++) {
        const ushort_t* Wmt_l   = Wmt   + (size_t)i * 65536;
        const ushort_t* W1t_l   = W1t   + (size_t)i * 262144;
        const ushort_t* W2t_l   = W2t   + (size_t)i * 131072;
        const float* g1_l = g1 + (size_t)i * 256;
        const float* b1_l = b1 + (size_t)i * 256;
        const float* g2_l = g2 + (size_t)i * 256;
        const float* b2_l = b2 + (size_t)i * 256;
        bool is_self = (i == 0 || i == 2);

        if (is_self) {
            kv_reduce_kernel<<<dim3(16, 32), 256, 0, stream>>>(QKV, ms0, ms1, KVb, KSb);
            attn_apply_kernel<<<NROWS, 256, 0, stream>>>(QKV, KVb, KSb, MSG);
        } else {
            gram_kernel<<<4225, 256, 0, stream>>>(Xbf, Gm);
            cross_fused_kernel<<<NROWS / 4, 256, 0, stream>>>(QKV, Gm, kp0, kp1, mc0, mc1, MSG);
        }

        // L1 = ln1(MSG @ Wm); T = tanh([Xbf|L1] @ W1); X += ln2(T @ W2);
        // Xbf = bf16(X); AND QKV for layer i+1 (fused; i==1 also zeroes
        // KVb/KSb for layer 2's kv_reduce).
        float* Xout = (i == 3) ? (float*)d_out : X;
        const ushort_t* Wqkv_next = (i < 3) ? (Wqkvt + (size_t)(i + 1) * 196608) : nullptr;
        float* zb = (i == 1) ? KVb : nullptr;
        mlp_ln_fused_kernel<<<NROWS / 32, 256, 0, stream>>>(
            MSG, Wmt_l, g1_l, b1_l, Xbf, W1t_l, W2t_l, g2_l, b2_l, Xbf, X, Xout,
            Wqkv_next, QKV, zb, 33792 / 4);
    }
}